// Round 1
// baseline (89.447 us; speedup 1.0000x reference)
//
#include <hip/hip_runtime.h>

// Problem: N=4096 dense fp32 matrix A (sparse content + self-loops).
// reference() returns 1.0 iff allclose(d[:,None]*A, (A^T @ diag(d))^T)
// where d = rowsum(A)^-0.5. Algebraically both sides are the identical
// IEEE product d[i]*A[i,j] (the dense GEMM sums exact zeros), so they
// differ only if NaNs appear, i.e. iff some rowsum is <=0 or NaN.
// => output = all(rowsum_i > 0) ? 1.0 : 0.0, computed in ONE pass over A.

#define NROWS 4096

__global__ void init_out_kernel(float* out) {
    out[0] = 1.0f;
}

// One 64-lane wave per row; float4 coalesced loads; shfl reduction.
__global__ __launch_bounds__(256) void rowsum_check_kernel(
        const float* __restrict__ A, float* __restrict__ out, int n) {
    const int gtid = blockIdx.x * blockDim.x + threadIdx.x;
    const int wave = gtid >> 6;        // global wave id = row id
    const int lane = threadIdx.x & 63;
    if (wave >= n) return;

    const float4* row = reinterpret_cast<const float4*>(A + (size_t)wave * n);
    const int nvec = n >> 2;           // 1024 float4 per row

    float s = 0.0f;
    #pragma unroll 4
    for (int i = lane; i < nvec; i += 64) {
        float4 v = row[i];
        s += (v.x + v.y) + (v.z + v.w);
    }

    // wave64 shuffle reduction
    #pragma unroll
    for (int off = 32; off > 0; off >>= 1) {
        s += __shfl_down(s, off, 64);
    }

    if (lane == 0) {
        // !(s > 0) catches s <= 0 and s == NaN. Benign race: every writer
        // stores the same 0.0f; init kernel ordered before on same stream.
        if (!(s > 0.0f)) out[0] = 0.0f;
    }
}

extern "C" void kernel_launch(void* const* d_in, const int* in_sizes, int n_in,
                              void* d_out, int out_size, void* d_ws, size_t ws_size,
                              hipStream_t stream) {
    const float* A = (const float*)d_in[0];
    float* out = (float*)d_out;

    init_out_kernel<<<1, 1, 0, stream>>>(out);

    const int n = NROWS;                       // 4096 (in_sizes[0] == n*n)
    const int waves = n;                       // one wave per row
    const int threads = 256;                   // 4 waves/block
    const int blocks = (waves * 64) / threads; // 1024
    rowsum_check_kernel<<<blocks, threads, 0, stream>>>(A, out, n);
}